// Round 9
// baseline (1243.842 us; speedup 1.0000x reference)
//
#include <hip/hip_runtime.h>
#include <hip/hip_bf16.h>
#include <math.h>

// Problem constants
#define Bq   128
#define Tq   512
#define Iq   300   // input dim
#define Hq   150   // hidden per dir
#define G3   450   // 3*H
#define Kq   6
#define Cq   300
#define D2   300   // 2*H
#define THq  20
#define CLSq 5

typedef __attribute__((ext_vector_type(8))) short short8;     // 8 bf16 (4 VGPR) MFMA A/B frag
typedef __attribute__((ext_vector_type(4))) float floatx4;    // MFMA C/D frag
typedef _Float16 h2v __attribute__((ext_vector_type(2)));     // packed half pair

// ---------------------------------------------------------------------------
// Kernel 0: fp32 -> bf16 cast (RNE). n4 = n/4.
// ---------------------------------------------------------------------------
__global__ __launch_bounds__(256) void cast_bf16_kernel(
    const float* __restrict__ in, __hip_bfloat16* __restrict__ out, int n4)
{
    const int i = blockIdx.x * 256 + threadIdx.x;
    if (i < n4) {
        float4 v = *(const float4*)(in + 4 * (size_t)i);
        out[4 * (size_t)i + 0] = __float2bfloat16(v.x);
        out[4 * (size_t)i + 1] = __float2bfloat16(v.y);
        out[4 * (size_t)i + 2] = __float2bfloat16(v.z);
        out[4 * (size_t)i + 3] = __float2bfloat16(v.w);
    }
}

// ---------------------------------------------------------------------------
// Kernel 0b: Whh fp32 -> fp16, rows padded 150 -> 152 halves.
// out[dir][450][152]; cols >= 150 are 0.
// ---------------------------------------------------------------------------
__global__ __launch_bounds__(256) void cast_whh_f16(
    const float* __restrict__ Wf, const float* __restrict__ Wb,
    unsigned short* __restrict__ out)
{
    const int idx = blockIdx.x * 256 + threadIdx.x;     // one half per thread
    const int total = 2 * G3 * 152;
    if (idx >= total) return;
    const int dir = idx / (G3 * 152);
    const int rem = idx % (G3 * 152);
    const int r = rem / 152, c = rem % 152;
    float v = 0.f;
    if (c < Hq) v = (dir ? Wb : Wf)[(size_t)r * Hq + c];
    out[idx] = __builtin_bit_cast(unsigned short, (_Float16)v);
}

// ---------------------------------------------------------------------------
// Kernel 1: gi GEMM via bf16 MFMA 16x16x32 (verified layouts, R6-proven).
// ---------------------------------------------------------------------------
#define LB 40

__global__ __launch_bounds__(256) void gi_gemm_mfma(
    const __hip_bfloat16* __restrict__ xb,    // [B][T][300] bf16
    const __hip_bfloat16* __restrict__ Wbf,   // [2][450][300] bf16
    const float* __restrict__ bf_, const float* __restrict__ bb_,
    float* __restrict__ gic, int t0f, int t0b, int tcShift)
{
    const int dir = blockIdx.z;
    const unsigned short* W = (const unsigned short*)(Wbf + (size_t)dir * G3 * Iq);
    const unsigned short* X = (const unsigned short*)xb;
    const float* bias = dir ? bb_ : bf_;
    const int t0 = dir ? t0b : t0f;
    const int TCr = 1 << tcShift;
    float* outb = gic + (size_t)dir * Bq * TCr * G3;

    const int m0 = blockIdx.y * 128;
    const int n0 = blockIdx.x * 128;
    const int tid  = threadIdx.x;
    const int wv   = tid >> 6, lane = tid & 63;
    const int wm   = wv & 1,  wn   = wv >> 1;
    const int quad = lane >> 4, mr = lane & 15;

    __shared__ __align__(16) unsigned short Ab[128 * LB];
    __shared__ __align__(16) unsigned short Bb[128 * LB];

    floatx4 acc[4][4];
    #pragma unroll
    for (int i = 0; i < 4; ++i)
        #pragma unroll
        for (int j = 0; j < 4; ++j)
            acc[i][j] = (floatx4){0.f, 0.f, 0.f, 0.f};

    for (int k0 = 0; k0 < 320; k0 += 32) {
        __syncthreads();
        #pragma unroll
        for (int i = 0; i < 4; ++i) {
            const int g = tid + 256 * i;         // 0..1023
            const int row = g >> 3, kq = g & 7;  // 4-bf16 granule
            const int k = k0 + kq * 4;
            const int r = m0 + row;
            const int bb2 = r >> tcShift, lt = r & (TCr - 1);
            ushort4 av = make_ushort4(0, 0, 0, 0);
            if (k < Iq)
                av = *(const ushort4*)(X + ((size_t)bb2 * Tq + t0 + lt) * Iq + k);
            *(ushort4*)&Ab[row * LB + kq * 4] = av;
            const int n = n0 + row;
            ushort4 bv = make_ushort4(0, 0, 0, 0);
            if (n < G3 && k < Iq)
                bv = *(const ushort4*)(W + (size_t)n * Iq + k);
            *(ushort4*)&Bb[row * LB + kq * 4] = bv;
        }
        __syncthreads();

        short8 af[4], bfr[4];
        #pragma unroll
        for (int i = 0; i < 4; ++i)
            af[i] = *(const short8*)&Ab[(wm * 64 + i * 16 + mr) * LB + quad * 8];
        #pragma unroll
        for (int j = 0; j < 4; ++j)
            bfr[j] = *(const short8*)&Bb[(wn * 64 + j * 16 + mr) * LB + quad * 8];
        #pragma unroll
        for (int i = 0; i < 4; ++i)
            #pragma unroll
            for (int j = 0; j < 4; ++j)
                acc[i][j] = __builtin_amdgcn_mfma_f32_16x16x32_bf16(
                    af[i], bfr[j], acc[i][j], 0, 0, 0);
    }

    #pragma unroll
    for (int j = 0; j < 4; ++j) {
        const int gn = n0 + wn * 64 + j * 16 + mr;
        if (gn >= G3) continue;
        const float bv = bias[gn];
        #pragma unroll
        for (int i = 0; i < 4; ++i) {
            const int mbase = m0 + wm * 64 + i * 16 + quad * 4;
            #pragma unroll
            for (int rg = 0; rg < 4; ++rg)
                outb[(size_t)(mbase + rg) * G3 + gn] = acc[i][j][rg] + bv;
        }
    }
}

// ---------------------------------------------------------------------------
// Kernel 2: GRU recurrence, gate-triple lanes + split weight streams (R15,
// resubmitted after R8-round infra failure — audited: no OOB, no divergent
// barrier, dbuf race-free, layout identical to the R14 run that passed).
// R14 post-mortem: 331us/dispatch = 3100 cyc/step = 267 LDS b128 instrs x
// ~11.7 cyc (m134) — LDS *instruction throughput* bound; the 19 h-broadcast
// reads per lane cost as much as full reads (half of all LDS instrs).
// R15 cuts LDS instructions ~2x and moves 1/3 of the weight stream to the
// idle VMEM pipe:
//  - lane t (150 lanes) owns the gate TRIPLE {t, 150+t, 300+t}: ONE set of
//    19 h-broadcast reads feeds 3 row-dots (h instrs 19x7 -> 19x3 waves),
//    and the gate fuses fully in-register -> sArr GONE.
//  - rows t, 150+t (r,z) read from LDS (38 b128/lane; R14-proven 304B-stride
//    conflict-free pattern); row 300+t (n) streamed from GLOBAL W16 —
//    static data, L2-hot (45.6KB/step/block; aggregate 13.7 TB/s < 34.5
//    ceiling), runs on the VMEM pipe CONCURRENTLY with LDS.
//  - h double-buffered (h2b[2]) -> ONE barrier/step.
//  - LDS: only rows 0..299 staged = 91.2 KB.
// ---------------------------------------------------------------------------
__device__ __forceinline__ float dot2h(unsigned int w, unsigned int h, float c)
{
#if __has_builtin(__builtin_amdgcn_fdot2)
    return __builtin_amdgcn_fdot2(__builtin_bit_cast(h2v, w),
                                  __builtin_bit_cast(h2v, h), c, false);
#else
    const h2v a = __builtin_bit_cast(h2v, w);
    const h2v b = __builtin_bit_cast(h2v, h);
    return c + (float)a.x * (float)b.x + (float)a.y * (float)b.y;
#endif
}

__global__ __launch_bounds__(512) void gru_rec(
    const float* __restrict__ gic,            // [2][B][TCr][450]
    const unsigned short* __restrict__ W16,   // [2][450][152] fp16
    const float* __restrict__ bhh_f, const float* __restrict__ bhh_b,
    float* __restrict__ hstate,               // [2][B][150]
    float* __restrict__ seq,                  // [B][T][300]
    int chunk, int tcShift)
{
    const int TCr = 1 << tcShift;
    const int bid = blockIdx.x;
    const int dir = bid & 1;
    const int b   = bid >> 1;
    const float* bhh = dir ? bhh_b : bhh_f;
    const int tid = threadIdx.x;
    const int t = tid;                        // gate-triple index
    const bool act = (t < Hq);

    __shared__ __align__(16) unsigned int Wlds[300 * 76];   // r,z rows: 91.2 KB
    __shared__ __align__(16) unsigned int h2b[2][80];       // h dbuf, packed f16

    // ---- stage rows 0..299 (r,z) into LDS: 5700 uint4, coalesced ----
    {
        const uint4* Wg = (const uint4*)(W16 + (size_t)dir * G3 * 152);
        uint4* Wl = (uint4*)Wlds;
        for (int i = tid; i < 300 * 19; i += 512) Wl[i] = Wg[i];
    }

    float* hs = hstate + (size_t)(dir * Bq + b) * Hq;
    float br = 0.f, bz = 0.f, bn = 0.f, hprev = 0.f;
    if (act) {
        br = bhh[t]; bz = bhh[150 + t]; bn = bhh[300 + t];
        if (chunk > 0) hprev = hs[t];
    }

    // ---- init h buffers: buf0 = h0 packed, buf1 = zeros (pads stay 0) ----
    if (tid < 160) {
        const int buf = (tid >= 80) ? 1 : 0;
        const int sl  = tid - 80 * buf;
        unsigned int v = 0;
        if (buf == 0 && sl < 75 && chunk > 0) {
            h2v p; p.x = (_Float16)hs[2 * sl]; p.y = (_Float16)hs[2 * sl + 1];
            v = __builtin_bit_cast(unsigned int, p);
        }
        h2b[buf][sl] = v;
    }
    __syncthreads();

    const float* gib = gic + (size_t)(dir * Bq + b) * TCr * G3;
    const int t0 = dir ? (Tq - TCr * (chunk + 1)) : (chunk * TCr);
    float* seqb = seq + (size_t)b * Tq * D2 + dir * Hq;

    const uint4* wlr = (const uint4*)(Wlds + (size_t)(act ? t : 0) * 76);
    const uint4* wlz = (const uint4*)(Wlds + (size_t)(150 + (act ? t : 0)) * 76);
    const uint4* wgn = (const uint4*)(W16 + (size_t)dir * G3 * 152
                                          + (size_t)(300 + (act ? t : 0)) * 152);

    int lt = dir ? (TCr - 1) : 0;
    float gr = 0.f, gz = 0.f, gn = 0.f;
    if (act) {
        gr = gib[(size_t)lt * G3 + t];
        gz = gib[(size_t)lt * G3 + 150 + t];
        gn = gib[(size_t)lt * G3 + 300 + t];
    }

    int cur = 0;
    for (int s = 0; s < TCr; ++s) {
        const int ltn = dir ? (TCr - 2 - s) : (s + 1);
        float nr = 0.f, nz = 0.f, nn = 0.f;
        if (s + 1 < TCr && act) {
            nr = gib[(size_t)ltn * G3 + t];
            nz = gib[(size_t)ltn * G3 + 150 + t];
            nn = gib[(size_t)ltn * G3 + 300 + t];
        }

        if (act) {
            const uint4* h4 = (const uint4*)h2b[cur];
            float ar0 = br + gr, ar1 = 0.f;
            float az0 = bz + gz, az1 = 0.f;
            float an0 = bn,      an1 = 0.f;     // gi_n stays in gn for tanh arg
            #pragma unroll
            for (int j = 0; j < 19; ++j) {
                const uint4 hh  = h4[j];     // LDS broadcast
                const uint4 wr_ = wlr[j];    // LDS, conflict-free (R14 pattern)
                const uint4 wz_ = wlz[j];    // LDS
                const uint4 wn_ = wgn[j];    // GLOBAL, L2-hot, VMEM pipe
                ar0 = dot2h(wr_.x, hh.x, ar0); ar1 = dot2h(wr_.y, hh.y, ar1);
                ar0 = dot2h(wr_.z, hh.z, ar0); ar1 = dot2h(wr_.w, hh.w, ar1);
                az0 = dot2h(wz_.x, hh.x, az0); az1 = dot2h(wz_.y, hh.y, az1);
                az0 = dot2h(wz_.z, hh.z, az0); az1 = dot2h(wz_.w, hh.w, az1);
                an0 = dot2h(wn_.x, hh.x, an0); an1 = dot2h(wn_.y, hh.y, an1);
                an0 = dot2h(wn_.z, hh.z, an0); an1 = dot2h(wn_.w, hh.w, an1);
            }
            const float r  = 1.f / (1.f + __expf(-(ar0 + ar1)));
            const float z  = 1.f / (1.f + __expf(-(az0 + az1)));
            const float nv = tanhf(gn + r * (an0 + an1));
            const float hn = (1.f - z) * nv + z * hprev;
            hprev = hn;
            ((_Float16*)h2b[cur ^ 1])[t] = (_Float16)hn;   // next step's h
            seqb[(size_t)(t0 + lt) * D2 + t] = hn;         // 600B coalesced
        }
        __syncthreads();   // writes to cur^1 visible; reads of cur complete

        gr = nr; gz = nz; gn = nn;
        lt = ltn; cur ^= 1;
    }

    if (act) hs[t] = hprev;
}

// ---------------------------------------------------------------------------
// Kernel 3a: ctxW[k][d] = battn[k][d] + sum_c attn_context[k][c]*Wattn[k][c][d]
// ---------------------------------------------------------------------------
__global__ void ctxw_kernel(
    const float* __restrict__ attn_context,
    const float* __restrict__ Wattn,
    const float* __restrict__ battn,
    float* __restrict__ ctxW)
{
    const int o = blockIdx.x * 256 + threadIdx.x;
    if (o >= Kq * D2) return;
    const int k = o / D2, d = o % D2;
    float acc = battn[o];
    const float* Wp = Wattn + ((size_t)k * (Cq + D2)) * D2 + d;
    for (int c = 0; c < Cq; ++c)
        acc += attn_context[k * Cq + c] * Wp[(size_t)c * D2];
    ctxW[o] = acc;
}

// ---------------------------------------------------------------------------
// Kernel 3b: context[b][k][:] = tanh(ctxW[k] + hidden[b] @ Wattn[k,300:,:])
// ---------------------------------------------------------------------------
__global__ __launch_bounds__(256) void ctx_compute(
    const float* __restrict__ seq,
    const float* __restrict__ Wattn,
    const float* __restrict__ ctxW,
    float* __restrict__ context,      // [B][6][300]
    float* __restrict__ normsq)       // [B][6]
{
    const int b = blockIdx.x;
    const int k = blockIdx.y;
    const int tid = threadIdx.x;
    const int lane = tid & 63, wv = tid >> 6;

    __shared__ float hb[304];
    __shared__ float red[4];

    for (int i = tid; i < D2; i += 256)
        hb[i] = (i < Hq) ? seq[((size_t)b * Tq + (Tq - 1)) * D2 + i]
                         : seq[(size_t)b * Tq * D2 + i];
    __syncthreads();

    float ssq = 0.f;
    for (int d = tid; d < D2; d += 256) {
        float acc = ctxW[k * D2 + d];
        const float* Wp = Wattn + ((size_t)k * (Cq + D2) + Cq) * D2 + d;
        for (int jj = 0; jj < D2; ++jj)
            acc += hb[jj] * Wp[(size_t)jj * D2];
        const float c = tanhf(acc);
        context[((size_t)b * Kq + k) * D2 + d] = c;
        ssq += c * c;
    }
    for (int off = 32; off > 0; off >>= 1) ssq += __shfl_xor(ssq, off, 64);
    if (lane == 0) red[wv] = ssq;
    __syncthreads();
    if (tid == 0) normsq[b * Kq + k] = red[0] + red[1] + red[2] + red[3];
}

// ---------------------------------------------------------------------------
// Kernel 3c: gram regularizer per b
// ---------------------------------------------------------------------------
__global__ __launch_bounds__(256) void gram_kernel(
    const float* __restrict__ context,
    const float* __restrict__ normsq,
    float* __restrict__ regbuf)
{
    const int b = blockIdx.x;
    const int tid = threadIdx.x;
    __shared__ float ctx[Kq * D2];
    __shared__ float Gm[36];

    for (int o = tid; o < Kq * D2; o += 256)
        ctx[o] = context[(size_t)b * Kq * D2 + o];
    __syncthreads();

    if (tid < 36) {
        const int k = tid / 6, jj = tid % 6;
        float g = 0.f;
        for (int d = 0; d < D2; ++d)
            g += ctx[k * D2 + d] * ctx[jj * D2 + d];
        const float nk = fmaxf(sqrtf(normsq[b * Kq + k]), 1e-12f);
        const float nj = fmaxf(sqrtf(normsq[b * Kq + jj]), 1e-12f);
        g /= (nk * nj);
        const float diff = g - ((k == jj) ? 1.f : 0.f);
        Gm[tid] = diff * diff;
    }
    __syncthreads();
    if (tid == 0) {
        float s = 0.f;
        for (int i = 0; i < 36; ++i) s += Gm[i];
        regbuf[b] = sqrtf(s);
    }
}

// ---------------------------------------------------------------------------
// Kernel 4a: energy[b][t][k] = seq[b][t] . context[b][k]   grid (8, B)
// ---------------------------------------------------------------------------
__global__ __launch_bounds__(256) void energy_kernel(
    const float* __restrict__ seq,
    const float* __restrict__ context,
    float* __restrict__ en)           // [B][512][6]
{
    const int tc = blockIdx.x;
    const int b  = blockIdx.y;
    const int tid = threadIdx.x;
    const int lane = tid & 63, wv = tid >> 6;

    __shared__ float ctx[Kq * D2];
    for (int o = tid; o < Kq * D2; o += 256)
        ctx[o] = context[(size_t)b * Kq * D2 + o];
    __syncthreads();

    const float* seqb = seq + (size_t)b * Tq * D2;
    for (int s = 0; s < 16; ++s) {
        const int tt = tc * 64 + s * 4 + wv;
        float acc[Kq] = {0.f,0.f,0.f,0.f,0.f,0.f};
        for (int d = lane; d < D2; d += 64) {
            const float sv = seqb[(size_t)tt * D2 + d];
            #pragma unroll
            for (int k = 0; k < Kq; ++k) acc[k] += sv * ctx[k * D2 + d];
        }
        #pragma unroll
        for (int k = 0; k < Kq; ++k) {
            float v = acc[k];
            for (int off = 32; off > 0; off >>= 1) v += __shfl_xor(v, off, 64);
            if (lane == 0) en[((size_t)b * Tq + tt) * Kq + k] = v;
        }
    }
}

// ---------------------------------------------------------------------------
// Kernel 4b: softmax over t per (b,k), in-place on en.  grid (B)
// ---------------------------------------------------------------------------
__global__ __launch_bounds__(256) void softmax_kernel(float* __restrict__ en)
{
    const int b = blockIdx.x;
    const int tid = threadIdx.x;
    const int lane = tid & 63, wv = tid >> 6;
    __shared__ float es[Tq * Kq];
    __shared__ float red[8];

    for (int o = tid; o < Tq * Kq; o += 256)
        es[o] = en[(size_t)b * Tq * Kq + o];
    __syncthreads();

    for (int k = 0; k < Kq; ++k) {
        float m = -1e30f;
        for (int tt = tid; tt < Tq; tt += 256) m = fmaxf(m, es[tt * Kq + k]);
        for (int off = 32; off > 0; off >>= 1) m = fmaxf(m, __shfl_xor(m, off, 64));
        if (lane == 0) red[wv] = m;
        __syncthreads();
        m = fmaxf(fmaxf(red[0], red[1]), fmaxf(red[2], red[3]));
        float ssum = 0.f;
        for (int tt = tid; tt < Tq; tt += 256) {
            const float e = __expf(es[tt * Kq + k] - m);
            es[tt * Kq + k] = e;
            ssum += e;
        }
        for (int off = 32; off > 0; off >>= 1) ssum += __shfl_xor(ssum, off, 64);
        if (lane == 0) red[4 + wv] = ssum;
        __syncthreads();
        const float inv = 1.f / (red[4] + red[5] + red[6] + red[7]);
        for (int tt = tid; tt < Tq; tt += 256) es[tt * Kq + k] *= inv;
        __syncthreads();
    }

    for (int o = tid; o < Tq * Kq; o += 256)
        en[(size_t)b * Tq * Kq + o] = es[o];
}

// ---------------------------------------------------------------------------
// Kernel 4c: pooled partials over 64-t chunks.  grid (8, B)
// ---------------------------------------------------------------------------
__global__ __launch_bounds__(256) void pooledp_kernel(
    const float* __restrict__ seq,
    const float* __restrict__ en,     // probs now
    float* __restrict__ partial)      // [B*8][1800]
{
    const int tc = blockIdx.x;
    const int b  = blockIdx.y;
    const int tid = threadIdx.x;
    const int lane = tid & 63, wv = tid >> 6;

    __shared__ float pr[64 * Kq];
    __shared__ float part[4][Kq * D2];   // 28.8 KB

    if (tid < 64 * Kq / 2) {
        pr[tid]       = en[((size_t)b * Tq + tc * 64) * Kq + tid];
        pr[tid + 192] = en[((size_t)b * Tq + tc * 64) * Kq + tid + 192];
    }
    __syncthreads();

    const float* seqb = seq + (size_t)b * Tq * D2;

    float pp[Kq][5];
    #pragma unroll
    for (int k = 0; k < Kq; ++k)
        #pragma unroll
        for (int q = 0; q < 5; ++q) pp[k][q] = 0.f;

    for (int s = 0; s < 16; ++s) {
        const int tl = s * 4 + wv;
        const int tt = tc * 64 + tl;
        float prr[Kq];
        #pragma unroll
        for (int k = 0; k < Kq; ++k) prr[k] = pr[tl * Kq + k];
        #pragma unroll
        for (int q = 0; q < 5; ++q) {
            const int d = lane + q * 64;
            const float sv = (d < D2) ? seqb[(size_t)tt * D2 + d] : 0.f;
            #pragma unroll
            for (int k = 0; k < Kq; ++k) pp[k][q] += prr[k] * sv;
        }
    }
    #pragma unroll
    for (int k = 0; k < Kq; ++k)
        #pragma unroll
        for (int q = 0; q < 5; ++q) {
            const int d = lane + q * 64;
            if (d < D2) part[wv][k * D2 + d] = pp[k][q];
        }
    __syncthreads();
    float* op = partial + ((size_t)b * 8 + tc) * (Kq * D2);
    for (int o = tid; o < Kq * D2; o += 256)
        op[o] = part[0][o] + part[1][o] + part[2][o] + part[3][o];
}

// ---------------------------------------------------------------------------
// Kernel 4d: final: pooled reduce -> topic -> logits -> softmax.  grid (B)
// ---------------------------------------------------------------------------
__global__ __launch_bounds__(256) void final_kernel(
    const float* __restrict__ partial,
    const float* __restrict__ Wtop,
    const float* __restrict__ btop,
    const float* __restrict__ Wout,
    const float* __restrict__ bout,
    float* __restrict__ outp)
{
    const int b = blockIdx.x;
    const int tid = threadIdx.x;
    __shared__ float pooled[Kq * D2];
    __shared__ float feats[Kq * THq];
    __shared__ float lsm[8];

    for (int o = tid; o < Kq * D2; o += 256) {
        float s = 0.f;
        #pragma unroll
        for (int c = 0; c < 8; ++c)
            s += partial[((size_t)b * 8 + c) * (Kq * D2) + o];
        pooled[o] = s;
    }
    __syncthreads();

    if (tid < Kq * THq) {
        const int k = tid / THq, hh = tid % THq;
        float acc = btop[tid];
        const float* wp = Wtop + (size_t)k * D2 * THq + hh;
        for (int d = 0; d < D2; ++d)
            acc += pooled[k * D2 + d] * wp[(size_t)d * THq];
        feats[tid] = fmaxf(acc, 0.f);
    }
    __syncthreads();

    if (tid < CLSq) {
        float acc = bout[tid];
        for (int f = 0; f < Kq * THq; ++f)
            acc += feats[f] * Wout[f * CLSq + tid];
        lsm[tid] = acc;
    }
    __syncthreads();
    if (tid < CLSq) {
        float m = lsm[0];
        for (int c = 1; c < CLSq; ++c) m = fmaxf(m, lsm[c]);
        float s = 0.f;
        for (int c = 0; c < CLSq; ++c) s += __expf(lsm[c] - m);
        outp[(size_t)b * CLSq + tid] = __expf(lsm[tid] - m) / s;
    }
}

// ---------------------------------------------------------------------------
// Kernel 5: reg = mean_b regbuf[b]  -> d_out[640]
// ---------------------------------------------------------------------------
__global__ void reg_final(const float* __restrict__ regbuf, float* __restrict__ outp)
{
    const int tid = threadIdx.x;   // 128 threads
    float v = regbuf[tid];
    for (int off = 32; off > 0; off >>= 1) v += __shfl_xor(v, off, 64);
    __shared__ float r2[2];
    if ((tid & 63) == 0) r2[tid >> 6] = v;
    __syncthreads();
    if (tid == 0) outp[Bq * CLSq] = (r2[0] + r2[1]) * (1.f / (float)Bq);
}

// ---------------------------------------------------------------------------
extern "C" void kernel_launch(void* const* d_in, const int* in_sizes, int n_in,
                              void* d_out, int out_size, void* d_ws, size_t ws_size,
                              hipStream_t stream)
{
    const float* x     = (const float*)d_in[0];
    const float* Wih_f = (const float*)d_in[1];
    const float* Whh_f = (const float*)d_in[2];
    const float* bih_f = (const float*)d_in[3];
    const float* bhh_f = (const float*)d_in[4];
    const float* Wih_b = (const float*)d_in[5];
    const float* Whh_b = (const float*)d_in[6];
    const float* bih_b = (const float*)d_in[7];
    const float* bhh_b = (const float*)d_in[8];
    const float* attn_context = (const float*)d_in[9];
    const float* Wattn = (const float*)d_in[10];
    const float* battn = (const float*)d_in[11];
    const float* Wtop  = (const float*)d_in[12];
    const float* btop  = (const float*)d_in[13];
    const float* Wout  = (const float*)d_in[14];
    const float* bout  = (const float*)d_in[15];
    float* outp = (float*)d_out;

    // fixed workspace layout (float units)
    float* ws       = (float*)d_ws;
    float* seqv     = ws;                                   // 19,660,800
    float* hstate   = seqv + (size_t)Bq * Tq * D2;          // 38,400
    float* ctxW     = hstate + (size_t)2 * Bq * Hq;         // 1,800
    float* context  = ctxW + Kq * D2;                       // 230,400
    float* regbuf   = context + (size_t)Bq * Kq * D2;       // 128
    float* normsq   = regbuf + Bq;                          // 768
    float* en       = normsq + Bq * Kq;                     // 393,216
    float* partial  = en + (size_t)Bq * Tq * Kq;            // 1,843,200
    __hip_bfloat16* xb16 = (__hip_bfloat16*)(partial + (size_t)Bq * 8 * Kq * D2); // 19,660,800 bf16
    __hip_bfloat16* Wb16 = xb16 + (size_t)Bq * Tq * Iq;     // 270,000 bf16
    unsigned short* W16 = (unsigned short*)(Wb16 + (size_t)2 * G3 * Iq); // 136,800 f16
    float* gi_chunk = (float*)(W16 + (size_t)2 * G3 * 152); // 115200*TCr fp32
    const size_t fixed_floats = (size_t)(gi_chunk - ws);

    // pick largest TCr in {256,128,64,32} that fits ws_size
    int tcShift = 5;
    for (int sh = 8; sh >= 5; --sh) {
        size_t need = (fixed_floats + (size_t)115200 * (1 << sh)) * 4;
        if (need <= ws_size) { tcShift = sh; break; }
    }
    const int TCr = 1 << tcShift;
    const int NL = Tq / TCr;

    // one-time casts: x/Wih -> bf16 (MFMA gi), Whh -> f16 padded (LDS gemv)
    cast_bf16_kernel<<<dim3((Bq * Tq * Iq / 4 + 255) / 256), 256, 0, stream>>>(
        x, xb16, Bq * Tq * Iq / 4);
    cast_bf16_kernel<<<dim3((G3 * Iq / 4 + 255) / 256), 256, 0, stream>>>(
        Wih_f, Wb16, G3 * Iq / 4);
    cast_bf16_kernel<<<dim3((G3 * Iq / 4 + 255) / 256), 256, 0, stream>>>(
        Wih_b, Wb16 + (size_t)G3 * Iq, G3 * Iq / 4);
    cast_whh_f16<<<dim3((2 * G3 * 152 + 255) / 256), 256, 0, stream>>>(
        Whh_f, Whh_b, W16);

    for (int c = 0; c < NL; ++c) {
        const int t0f = c * TCr;
        const int t0b = Tq - TCr * (c + 1);
        gi_gemm_mfma<<<dim3(4, Bq * TCr / 128, 2), 256, 0, stream>>>(
            xb16, Wb16, bih_f, bih_b, gi_chunk, t0f, t0b, tcShift);
        gru_rec<<<dim3(2 * Bq), 512, 0, stream>>>(
            gi_chunk, W16, bhh_f, bhh_b, hstate, seqv, c, tcShift);
    }

    ctxw_kernel<<<dim3((Kq * D2 + 255) / 256), 256, 0, stream>>>(
        attn_context, Wattn, battn, ctxW);
    ctx_compute<<<dim3(Bq, Kq), 256, 0, stream>>>(seqv, Wattn, ctxW, context, normsq);
    gram_kernel<<<dim3(Bq), 256, 0, stream>>>(context, normsq, regbuf);
    energy_kernel<<<dim3(8, Bq), 256, 0, stream>>>(seqv, context, en);
    softmax_kernel<<<dim3(Bq), 256, 0, stream>>>(en);
    pooledp_kernel<<<dim3(8, Bq), 256, 0, stream>>>(seqv, en, partial);
    final_kernel<<<dim3(Bq), 256, 0, stream>>>(partial, Wtop, btop, Wout, bout, outp);
    reg_final<<<dim3(1), 128, 0, stream>>>(regbuf, outp);
}